// Round 4
// baseline (1761.667 us; speedup 1.0000x reference)
//
#include <hip/hip_runtime.h>
#include <stdint.h>

#define NN 50000
#define EE 800000
#define DH 128
#define NC 40
#define KCAT (14*DH)   // 1792
#define CAP 64         // ELL capacity; deg ~ Binom(800k,1/50k), P(deg>64) ~ 1e-18

typedef __bf16 bf16x8 __attribute__((ext_vector_type(8)));
typedef float floatx4 __attribute__((ext_vector_type(4)));

__device__ __forceinline__ float bf2f(unsigned short u) {
  union { uint32_t i; float f; } v; v.i = ((uint32_t)u) << 16; return v.f;
}
__device__ __forceinline__ unsigned short f2bf(float f) {
  union { float f; uint32_t i; } v; v.f = f;
  uint32_t x = v.i;
  uint32_t r = (x + 0x7fffu + ((x >> 16) & 1u)) >> 16;  // RNE
  return (unsigned short)r;
}

// ---------------- utility ----------------
__global__ void zero_i32(int* p, int n) {
  int i = blockIdx.x * blockDim.x + threadIdx.x;
  if (i < n) p[i] = 0;
}

// Probe x's first 4096 16-bit words. bf16 N(0,1): zero wild exponents.
// fp32 read as words: low halves uniform -> ~44% wild.  [confirmed fp32 in R3]
__global__ void detect_dtype(const unsigned short* xw, int* wildcnt) {
  int t = threadIdx.x;
  int wild = 0;
  for (int i = t; i < 4096; i += 256) {
    unsigned e = (xw[i] >> 7) & 0xFF;
    if (e >= 0x90) wild++;
  }
  if (wild) atomicAdd(wildcnt, wild);
}

// canonicalize a float tensor to bf16 (input fp32 or bf16, per flag)
__global__ void convert_f(const void* in, unsigned short* outp, int n, const int* flag) {
  bool isf32 = (*flag) > 32;
  for (int i = blockIdx.x * blockDim.x + threadIdx.x; i < n;
       i += gridDim.x * blockDim.x) {
    outp[i] = isf32 ? f2bf(((const float*)in)[i]) : ((const unsigned short*)in)[i];
  }
}

// B[L][K][M] -> BT[L][Mpad][K] (bf16 out), zero-pad n>=M
__global__ void transpose_w(const void* B, unsigned short* BT,
                            int L, int K, int M, int Mpad, const int* flag) {
  bool isf32 = (*flag) > 32;
  int total = L * Mpad * K;
  for (int idx = blockIdx.x * blockDim.x + threadIdx.x; idx < total;
       idx += gridDim.x * blockDim.x) {
    int k = idx % K;
    int n = (idx / K) % Mpad;
    int l = idx / (K * Mpad);
    unsigned short v = 0;
    if (n < M) {
      size_t si = (size_t)l * K * M + (size_t)k * M + n;
      v = isf32 ? f2bf(((const float*)B)[si]) : ((const unsigned short*)B)[si];
    }
    BT[idx] = v;
  }
}

// ---------------- ELL adjacency build ----------------
__global__ void build_ell(const int* __restrict__ src, const int* __restrict__ dst,
                          const void* __restrict__ w,
                          int* __restrict__ cnt, int2* __restrict__ ell,
                          const int* __restrict__ flag) {
  bool isf32 = (*flag) > 32;
  int e = blockIdx.x * blockDim.x + threadIdx.x;
  if (e >= EE) return;
  int d = dst[e];
  if ((unsigned)d >= NN) return;
  int p = atomicAdd(&cnt[d], 1);
  if (p >= CAP) return;
  int s = src[e];
  float wf = isf32 ? ((const float*)w)[e] : bf2f(((const unsigned short*)w)[e]);
  if ((unsigned)s >= NN) { s = 0; wf = 0.f; }
  union { float f; int i; } wv; wv.f = wf;
  ell[(size_t)d * CAP + p] = make_int2(s, wv.i);
}

// ---------------- GEMM: C[N,128] = A[N,K] @ B[K,128] (+bias), BT pre-transposed [128][K] ----------------
__global__ __launch_bounds__(256) void gemm_h(
    const unsigned short* __restrict__ A, int lda,
    const unsigned short* __restrict__ BT, int K,
    unsigned short* __restrict__ C, const unsigned short* __restrict__ bias) {
  __shared__ unsigned short As[128][40];
  __shared__ unsigned short Bs[128][40];
  int t = threadIdx.x;
  int wave = t >> 6, lane = t & 63;
  int wy = wave >> 1, wx = wave & 1;
  int q = lane >> 4, mn = lane & 15;
  int r0 = blockIdx.x * 128;
  floatx4 acc[4][4];
  floatx4 zf = {0.f, 0.f, 0.f, 0.f};
  #pragma unroll
  for (int i = 0; i < 4; ++i)
    #pragma unroll
    for (int j = 0; j < 4; ++j) acc[i][j] = zf;

  int arow = t >> 2;
  int akc = (t & 3) << 3;

  for (int k0 = 0; k0 < K; k0 += 32) {
    #pragma unroll
    for (int h = 0; h < 2; ++h) {
      int r = arow + h * 64;
      uint4 v = make_uint4(0, 0, 0, 0);
      if (r0 + r < NN) v = *(const uint4*)(A + (size_t)(r0 + r) * lda + k0 + akc);
      *(uint4*)(&As[r][akc]) = v;
    }
    #pragma unroll
    for (int h = 0; h < 2; ++h) {
      int n = arow + h * 64;
      uint4 v = *(const uint4*)(BT + (size_t)n * K + k0 + akc);
      *(uint4*)(&Bs[n][akc]) = v;
    }
    __syncthreads();
    bf16x8 fa[4], fb[4];
    #pragma unroll
    for (int i = 0; i < 4; ++i) fa[i] = *(const bf16x8*)(&As[wy * 64 + i * 16 + mn][q * 8]);
    #pragma unroll
    for (int j = 0; j < 4; ++j) fb[j] = *(const bf16x8*)(&Bs[wx * 64 + j * 16 + mn][q * 8]);
    #pragma unroll
    for (int i = 0; i < 4; ++i)
      #pragma unroll
      for (int j = 0; j < 4; ++j)
        acc[i][j] = __builtin_amdgcn_mfma_f32_16x16x32_bf16(fa[i], fb[j], acc[i][j], 0, 0, 0);
    __syncthreads();
  }
  // C/D: col = lane&15, row = (lane>>4)*4 + reg
  #pragma unroll
  for (int i = 0; i < 4; ++i) {
    int rbase = r0 + wy * 64 + i * 16 + q * 4;
    #pragma unroll
    for (int j = 0; j < 4; ++j) {
      int col = wx * 64 + j * 16 + mn;
      float badd = bias ? bf2f(bias[col]) : 0.0f;
      #pragma unroll
      for (int rr = 0; rr < 4; ++rr) {
        int row = rbase + rr;
        if (row < NN) C[(size_t)row * 128 + col] = f2bf(acc[i][j][rr] + badd);
      }
    }
  }
}

// ---------------- final GEMM: s15[N,40] = xcat[N,1792] @ W15 (fp32 out) ----------------
__global__ __launch_bounds__(256) void gemm_cat(
    const unsigned short* __restrict__ A, const unsigned short* __restrict__ BT /*[48][1792]*/,
    float* __restrict__ C) {
  __shared__ unsigned short As[128][40];
  __shared__ unsigned short Bs[48][40];
  int t = threadIdx.x;
  int wave = t >> 6, lane = t & 63;
  int q = lane >> 4, mn = lane & 15;
  int r0 = blockIdx.x * 128;
  floatx4 acc[2][3];
  floatx4 zf = {0.f, 0.f, 0.f, 0.f};
  #pragma unroll
  for (int i = 0; i < 2; ++i)
    #pragma unroll
    for (int j = 0; j < 3; ++j) acc[i][j] = zf;

  int arow = t >> 2;
  int akc = (t & 3) << 3;

  for (int k0 = 0; k0 < KCAT; k0 += 32) {
    #pragma unroll
    for (int h = 0; h < 2; ++h) {
      int r = arow + h * 64;
      uint4 v = make_uint4(0, 0, 0, 0);
      if (r0 + r < NN) v = *(const uint4*)(A + (size_t)(r0 + r) * KCAT + k0 + akc);
      *(uint4*)(&As[r][akc]) = v;
    }
    if (t < 192) {
      uint4 v = *(const uint4*)(BT + (size_t)arow * KCAT + k0 + akc);
      *(uint4*)(&Bs[arow][akc]) = v;
    }
    __syncthreads();
    bf16x8 fa[2], fb[3];
    #pragma unroll
    for (int i = 0; i < 2; ++i) fa[i] = *(const bf16x8*)(&As[wave * 32 + i * 16 + mn][q * 8]);
    #pragma unroll
    for (int j = 0; j < 3; ++j) fb[j] = *(const bf16x8*)(&Bs[j * 16 + mn][q * 8]);
    #pragma unroll
    for (int i = 0; i < 2; ++i)
      #pragma unroll
      for (int j = 0; j < 3; ++j)
        acc[i][j] = __builtin_amdgcn_mfma_f32_16x16x32_bf16(fa[i], fb[j], acc[i][j], 0, 0, 0);
    __syncthreads();
  }
  #pragma unroll
  for (int i = 0; i < 2; ++i) {
    int rbase = r0 + wave * 32 + i * 16 + q * 4;
    #pragma unroll
    for (int j = 0; j < 3; ++j) {
      int col = j * 16 + mn;
      #pragma unroll
      for (int rr = 0; rr < 4; ++rr) {
        int row = rbase + rr;
        if (row < NN && col < NC) C[(size_t)row * NC + col] = acc[i][j][rr];
      }
    }
  }
}

// ---------------- SPMM fused: out = relu(agg + b) + res ----------------
__global__ __launch_bounds__(128) void spmm_layer(
    const unsigned short* __restrict__ support, const int* __restrict__ cnt,
    const int2* __restrict__ ell, const unsigned short* __restrict__ bias,
    const unsigned short* __restrict__ res, int res_stride,
    unsigned short* __restrict__ out, int out_stride) {
  int row = blockIdx.x;
  int f = threadIdx.x;
  int n = cnt[row];
  if (n > CAP) n = CAP;
  const int2* erow = ell + (size_t)row * CAP;
  float acc = 0.f;
  for (int j = 0; j < n; ++j) {
    int2 ed = erow[j];
    union { int i; float f; } wv; wv.i = ed.y;
    acc += wv.f * bf2f(support[(size_t)ed.x * 128 + f]);
  }
  float v = acc + bf2f(bias[f]);
  v = fmaxf(v, 0.f) + bf2f(res[(size_t)row * res_stride + f]);
  out[(size_t)row * out_stride + f] = f2bf(v);
}

// ---------------- final SPMM (d=40) + bias + log_softmax -> FP32 output ----------------
__global__ __launch_bounds__(256) void spmm_softmax_out(
    const float* __restrict__ s15, const int* __restrict__ cnt,
    const int2* __restrict__ ell, const unsigned short* __restrict__ bias,
    float* __restrict__ out) {
  int wave = threadIdx.x >> 6, lane = threadIdx.x & 63;
  int row = blockIdx.x * 4 + wave;
  if (row >= NN) return;
  int n = cnt[row];
  if (n > CAP) n = CAP;
  const int2* erow = ell + (size_t)row * CAP;
  float acc = 0.f;
  if (lane < NC) {
    for (int j = 0; j < n; ++j) {
      int2 ed = erow[j];
      union { int i; float f; } wv; wv.i = ed.y;
      acc += wv.f * s15[(size_t)ed.x * NC + lane];
    }
    acc += bf2f(bias[lane]);
  }
  float v = (lane < NC) ? acc : -3.0e38f;
  float m = v;
  #pragma unroll
  for (int off = 32; off > 0; off >>= 1) m = fmaxf(m, __shfl_xor(m, off));
  float e = (lane < NC) ? expf(v - m) : 0.f;
  float sum = e;
  #pragma unroll
  for (int off = 32; off > 0; off >>= 1) sum += __shfl_xor(sum, off);
  if (lane < NC) out[(size_t)row * NC + lane] = v - m - logf(sum);  // fp32 write
}

extern "C" void kernel_launch(void* const* d_in, const int* in_sizes, int n_in,
                              void* d_out, int out_size, void* d_ws, size_t ws_size,
                              hipStream_t stream) {
  const void* x   = d_in[0];
  const int* esrc = (const int*)d_in[1];
  const int* edst = (const int*)d_in[2];
  const void* ew  = d_in[3];
  const void* W0  = d_in[4];
  const void* b0  = d_in[5];
  const void* W1  = d_in[6];
  const void* b1  = d_in[7];
  const void* Wm  = d_in[8];
  const void* bm  = d_in[9];
  const void* W15 = d_in[10];
  const void* b15 = d_in[11];
  float* out = (float*)d_out;   // reference output dtype = float32

  char* ws = (char*)d_ws;
  size_t off = 0;
  auto alloc = [&](size_t bytes) -> void* {
    void* p = ws + off;
    off = (off + bytes + 255) & ~(size_t)255;
    return p;
  };
  unsigned short* xcat = (unsigned short*)alloc((size_t)NN * KCAT * 2);  // x14|...|x1
  unsigned short* xbf  = (unsigned short*)alloc((size_t)NN * 256 * 2);
  unsigned short* supp = (unsigned short*)alloc((size_t)NN * DH * 2);
  unsigned short* zbuf = (unsigned short*)alloc((size_t)NN * DH * 2);
  float* s15           = (float*)alloc((size_t)NN * NC * 4);
  int* counts          = (int*)alloc((size_t)(NN + 1) * 4);  // [NN] = dtype wild count
  int2* ell            = (int2*)alloc((size_t)NN * CAP * 8);
  unsigned short* W0T  = (unsigned short*)alloc((size_t)256 * 128 * 2);
  unsigned short* W1T  = (unsigned short*)alloc((size_t)256 * 128 * 2);
  unsigned short* WmT  = (unsigned short*)alloc((size_t)13 * 128 * 128 * 2);
  unsigned short* W15T = (unsigned short*)alloc((size_t)48 * 1792 * 2);
  unsigned short* bb   = (unsigned short*)alloc((size_t)(128 + 128 + 13 * 128 + 40) * 2);
  if (off > ws_size) return;  // signature: output stays zero
  int* flag = counts + NN;
  unsigned short* b0b  = bb;
  unsigned short* b1b  = bb + 128;
  unsigned short* bmb  = bb + 256;
  unsigned short* b15b = bb + 256 + 13 * 128;

  zero_i32<<<197, 256, 0, stream>>>(counts, NN + 1);
  detect_dtype<<<1, 256, 0, stream>>>((const unsigned short*)x, flag);
  transpose_w<<<128, 256, 0, stream>>>(W0, W0T, 1, 256, 128, 128, flag);
  transpose_w<<<128, 256, 0, stream>>>(W1, W1T, 1, 256, 128, 128, flag);
  transpose_w<<<832, 256, 0, stream>>>(Wm, WmT, 13, 128, 128, 128, flag);
  transpose_w<<<336, 256, 0, stream>>>(W15, W15T, 1, 1792, 40, 48, flag);
  convert_f<<<2048, 256, 0, stream>>>(x, xbf, NN * 256, flag);
  convert_f<<<1, 128, 0, stream>>>(b0, b0b, 128, flag);
  convert_f<<<1, 128, 0, stream>>>(b1, b1b, 128, flag);
  convert_f<<<7, 256, 0, stream>>>(bm, bmb, 13 * 128, flag);
  convert_f<<<1, 64, 0, stream>>>(b15, b15b, 40, flag);
  build_ell<<<3125, 256, 0, stream>>>(esrc, edst, ew, counts, ell, flag);

  int gb = (NN + 127) / 128;  // 391
  gemm_h<<<gb, 256, 0, stream>>>(xbf, 256, W0T, 256, zbuf, b0b);      // z = x@W0+b0
  gemm_h<<<gb, 256, 0, stream>>>(xbf, 256, W1T, 256, supp, nullptr);  // supp = x@W1
  spmm_layer<<<NN, 128, 0, stream>>>(supp, counts, ell, b1b, zbuf, DH,
                                     xcat + 13 * DH, KCAT);           // x1
  for (int l = 0; l < 13; ++l) {
    gemm_h<<<gb, 256, 0, stream>>>(xcat + (13 - l) * DH, KCAT, WmT + l * 128 * 128, 128,
                                   supp, nullptr);
    spmm_layer<<<NN, 128, 0, stream>>>(supp, counts, ell, bmb + l * DH,
                                       xcat + (13 - l) * DH, KCAT,
                                       xcat + (12 - l) * DH, KCAT);
  }
  gemm_cat<<<gb, 256, 0, stream>>>(xcat, W15T, s15);
  spmm_softmax_out<<<(NN + 3) / 4, 256, 0, stream>>>(s15, counts, ell, b15b, out);
}

// Round 5
// 965.887 us; speedup vs baseline: 1.8239x; 1.8239x over previous
//
#include <hip/hip_runtime.h>
#include <stdint.h>

#define NN 50000
#define EE 800000
#define DH 128
#define NC 40
#define KCAT (14*DH)   // 1792
#define CAP 64         // ELL capacity; deg ~ Binom(800k,1/50k), P(deg>64) ~ 1e-18

typedef __bf16 bf16x8 __attribute__((ext_vector_type(8)));
typedef float floatx4 __attribute__((ext_vector_type(4)));

__device__ __forceinline__ float bf2f(unsigned short u) {
  union { uint32_t i; float f; } v; v.i = ((uint32_t)u) << 16; return v.f;
}
__device__ __forceinline__ unsigned short f2bf(float f) {
  union { float f; uint32_t i; } v; v.f = f;
  uint32_t x = v.i;
  uint32_t r = (x + 0x7fffu + ((x >> 16) & 1u)) >> 16;  // RNE
  return (unsigned short)r;
}

// ---------------- utility ----------------
__global__ void zero_i32(int* p, int n) {
  int i = blockIdx.x * blockDim.x + threadIdx.x;
  if (i < n) p[i] = 0;
}

// Probe x's first 4096 16-bit words (R3: confirmed fp32 inputs; keep dtype-agnostic).
__global__ void detect_dtype(const unsigned short* xw, int* wildcnt) {
  int t = threadIdx.x;
  int wild = 0;
  for (int i = t; i < 4096; i += 256) {
    unsigned e = (xw[i] >> 7) & 0xFF;
    if (e >= 0x90) wild++;
  }
  if (wild) atomicAdd(wildcnt, wild);
}

__global__ void convert_f(const void* in, unsigned short* outp, int n, const int* flag) {
  bool isf32 = (*flag) > 32;
  for (int i = blockIdx.x * blockDim.x + threadIdx.x; i < n;
       i += gridDim.x * blockDim.x) {
    outp[i] = isf32 ? f2bf(((const float*)in)[i]) : ((const unsigned short*)in)[i];
  }
}

// B[L][K][M] -> BT[L][Mpad][K] (bf16 out), zero-pad n>=M
__global__ void transpose_w(const void* B, unsigned short* BT,
                            int L, int K, int M, int Mpad, const int* flag) {
  bool isf32 = (*flag) > 32;
  int total = L * Mpad * K;
  for (int idx = blockIdx.x * blockDim.x + threadIdx.x; idx < total;
       idx += gridDim.x * blockDim.x) {
    int k = idx % K;
    int n = (idx / K) % Mpad;
    int l = idx / (K * Mpad);
    unsigned short v = 0;
    if (n < M) {
      size_t si = (size_t)l * K * M + (size_t)k * M + n;
      v = isf32 ? f2bf(((const float*)B)[si]) : ((const unsigned short*)B)[si];
    }
    BT[idx] = v;
  }
}

// ---------------- ELL adjacency build ----------------
__global__ void build_ell(const int* __restrict__ src, const int* __restrict__ dst,
                          const void* __restrict__ w,
                          int* __restrict__ cnt, int2* __restrict__ ell,
                          const int* __restrict__ flag) {
  bool isf32 = (*flag) > 32;
  int e = blockIdx.x * blockDim.x + threadIdx.x;
  if (e >= EE) return;
  int d = dst[e];
  if ((unsigned)d >= NN) return;
  int p = atomicAdd(&cnt[d], 1);
  if (p >= CAP) return;
  int s = src[e];
  float wf = isf32 ? ((const float*)w)[e] : bf2f(((const unsigned short*)w)[e]);
  if ((unsigned)s >= NN) { s = 0; wf = 0.f; }
  union { float f; int i; } wv; wv.f = wf;
  ell[(size_t)d * CAP + p] = make_int2(s, wv.i);
}

// ---------------- GEMM: C[N,128] = A[N,K] @ B[K,128] (+bias), BT pre-transposed [128][K] ----------------
__global__ __launch_bounds__(256) void gemm_h(
    const unsigned short* __restrict__ A, int lda,
    const unsigned short* __restrict__ BT, int K,
    unsigned short* __restrict__ C, const unsigned short* __restrict__ bias) {
  __shared__ unsigned short As[128][40];
  __shared__ unsigned short Bs[128][40];
  int t = threadIdx.x;
  int wave = t >> 6, lane = t & 63;
  int wy = wave >> 1, wx = wave & 1;
  int q = lane >> 4, mn = lane & 15;
  int r0 = blockIdx.x * 128;
  floatx4 acc[4][4];
  floatx4 zf = {0.f, 0.f, 0.f, 0.f};
  #pragma unroll
  for (int i = 0; i < 4; ++i)
    #pragma unroll
    for (int j = 0; j < 4; ++j) acc[i][j] = zf;

  int arow = t >> 2;
  int akc = (t & 3) << 3;

  for (int k0 = 0; k0 < K; k0 += 32) {
    #pragma unroll
    for (int h = 0; h < 2; ++h) {
      int r = arow + h * 64;
      uint4 v = make_uint4(0, 0, 0, 0);
      if (r0 + r < NN) v = *(const uint4*)(A + (size_t)(r0 + r) * lda + k0 + akc);
      *(uint4*)(&As[r][akc]) = v;
    }
    #pragma unroll
    for (int h = 0; h < 2; ++h) {
      int n = arow + h * 64;
      uint4 v = *(const uint4*)(BT + (size_t)n * K + k0 + akc);
      *(uint4*)(&Bs[n][akc]) = v;
    }
    __syncthreads();
    bf16x8 fa[4], fb[4];
    #pragma unroll
    for (int i = 0; i < 4; ++i) fa[i] = *(const bf16x8*)(&As[wy * 64 + i * 16 + mn][q * 8]);
    #pragma unroll
    for (int j = 0; j < 4; ++j) fb[j] = *(const bf16x8*)(&Bs[wx * 64 + j * 16 + mn][q * 8]);
    #pragma unroll
    for (int i = 0; i < 4; ++i)
      #pragma unroll
      for (int j = 0; j < 4; ++j)
        acc[i][j] = __builtin_amdgcn_mfma_f32_16x16x32_bf16(fa[i], fb[j], acc[i][j], 0, 0, 0);
    __syncthreads();
  }
  // C/D: col = lane&15, row = (lane>>4)*4 + reg
  #pragma unroll
  for (int i = 0; i < 4; ++i) {
    int rbase = r0 + wy * 64 + i * 16 + q * 4;
    #pragma unroll
    for (int j = 0; j < 4; ++j) {
      int col = wx * 64 + j * 16 + mn;
      float badd = bias ? bf2f(bias[col]) : 0.0f;
      #pragma unroll
      for (int rr = 0; rr < 4; ++rr) {
        int row = rbase + rr;
        if (row < NN) C[(size_t)row * 128 + col] = f2bf(acc[i][j][rr] + badd);
      }
    }
  }
}

// ---------------- final GEMM: s15[N,40] = xcat[N,1792] @ W15 (fp32 out) ----------------
__global__ __launch_bounds__(256) void gemm_cat(
    const unsigned short* __restrict__ A, const unsigned short* __restrict__ BT /*[48][1792]*/,
    float* __restrict__ C) {
  __shared__ unsigned short As[128][40];
  __shared__ unsigned short Bs[48][40];
  int t = threadIdx.x;
  int wave = t >> 6, lane = t & 63;
  int q = lane >> 4, mn = lane & 15;
  int r0 = blockIdx.x * 128;
  floatx4 acc[2][3];
  floatx4 zf = {0.f, 0.f, 0.f, 0.f};
  #pragma unroll
  for (int i = 0; i < 2; ++i)
    #pragma unroll
    for (int j = 0; j < 3; ++j) acc[i][j] = zf;

  int arow = t >> 2;
  int akc = (t & 3) << 3;

  for (int k0 = 0; k0 < KCAT; k0 += 32) {
    #pragma unroll
    for (int h = 0; h < 2; ++h) {
      int r = arow + h * 64;
      uint4 v = make_uint4(0, 0, 0, 0);
      if (r0 + r < NN) v = *(const uint4*)(A + (size_t)(r0 + r) * KCAT + k0 + akc);
      *(uint4*)(&As[r][akc]) = v;
    }
    if (t < 192) {
      uint4 v = *(const uint4*)(BT + (size_t)arow * KCAT + k0 + akc);
      *(uint4*)(&Bs[arow][akc]) = v;
    }
    __syncthreads();
    bf16x8 fa[2], fb[3];
    #pragma unroll
    for (int i = 0; i < 2; ++i) fa[i] = *(const bf16x8*)(&As[wave * 32 + i * 16 + mn][q * 8]);
    #pragma unroll
    for (int j = 0; j < 3; ++j) fb[j] = *(const bf16x8*)(&Bs[j * 16 + mn][q * 8]);
    #pragma unroll
    for (int i = 0; i < 2; ++i)
      #pragma unroll
      for (int j = 0; j < 3; ++j)
        acc[i][j] = __builtin_amdgcn_mfma_f32_16x16x32_bf16(fa[i], fb[j], acc[i][j], 0, 0, 0);
    __syncthreads();
  }
  #pragma unroll
  for (int i = 0; i < 2; ++i) {
    int rbase = r0 + wave * 32 + i * 16 + q * 4;
    #pragma unroll
    for (int j = 0; j < 3; ++j) {
      int col = j * 16 + mn;
      #pragma unroll
      for (int rr = 0; rr < 4; ++rr) {
        int row = rbase + rr;
        if (row < NN && col < NC) C[(size_t)row * NC + col] = acc[i][j][rr];
      }
    }
  }
}

// ---------------- SPMM fused: out = relu(agg + b) + res ----------------
// One WAVE per row; lane covers features {2*lane, 2*lane+1} (packed uint).
// All <=64 ELL slots staged in registers with ONE dwordx2/lane, broadcast via shfl.
__global__ __launch_bounds__(256) void spmm_layer(
    const unsigned short* __restrict__ support, const int* __restrict__ cnt,
    const int2* __restrict__ ell, const unsigned short* __restrict__ bias,
    const unsigned short* __restrict__ res, int res_stride,
    unsigned short* __restrict__ out, int out_stride) {
  int wave = threadIdx.x >> 6, lane = threadIdx.x & 63;
  int row = blockIdx.x * 4 + wave;
  if (row >= NN) return;
  int n = cnt[row];
  if (n > CAP) n = CAP;
  int2 ev = ell[(size_t)row * CAP + lane];  // lane j holds edge j
  float a0 = 0.f, a1 = 0.f;
  int j = 0;
  for (; j + 8 <= n; j += 8) {
    uint32_t g[8];
    int sidx[8];
    #pragma unroll
    for (int u = 0; u < 8; ++u) sidx[u] = __shfl(ev.x, j + u);
    #pragma unroll
    for (int u = 0; u < 8; ++u)
      g[u] = *(const uint32_t*)(support + (size_t)sidx[u] * DH + 2 * lane);
    #pragma unroll
    for (int u = 0; u < 8; ++u) {
      union { int i; float f; } wv; wv.i = __shfl(ev.y, j + u);
      a0 += wv.f * bf2f((unsigned short)(g[u] & 0xffff));
      a1 += wv.f * bf2f((unsigned short)(g[u] >> 16));
    }
  }
  for (; j < n; ++j) {
    int s = __shfl(ev.x, j);
    union { int i; float f; } wv; wv.i = __shfl(ev.y, j);
    uint32_t g = *(const uint32_t*)(support + (size_t)s * DH + 2 * lane);
    a0 += wv.f * bf2f((unsigned short)(g & 0xffff));
    a1 += wv.f * bf2f((unsigned short)(g >> 16));
  }
  uint32_t bw = *(const uint32_t*)(bias + 2 * lane);
  uint32_t rw = *(const uint32_t*)(res + (size_t)row * res_stride + 2 * lane);
  float v0 = fmaxf(a0 + bf2f((unsigned short)(bw & 0xffff)), 0.f) +
             bf2f((unsigned short)(rw & 0xffff));
  float v1 = fmaxf(a1 + bf2f((unsigned short)(bw >> 16)), 0.f) +
             bf2f((unsigned short)(rw >> 16));
  uint32_t o = (uint32_t)f2bf(v0) | ((uint32_t)f2bf(v1) << 16);
  *(uint32_t*)(out + (size_t)row * out_stride + 2 * lane) = o;
}

// ---------------- final SPMM (d=40) + bias + log_softmax -> FP32 output ----------------
__global__ __launch_bounds__(256) void spmm_softmax_out(
    const float* __restrict__ s15, const int* __restrict__ cnt,
    const int2* __restrict__ ell, const unsigned short* __restrict__ bias,
    float* __restrict__ out) {
  int wave = threadIdx.x >> 6, lane = threadIdx.x & 63;
  int row = blockIdx.x * 4 + wave;
  if (row >= NN) return;
  int n = cnt[row];
  if (n > CAP) n = CAP;
  int2 ev = ell[(size_t)row * CAP + lane];
  int fl = lane < NC ? lane : NC - 1;  // keep all 64 lanes convergent for shfl
  float acc = 0.f;
  int j = 0;
  for (; j + 4 <= n; j += 4) {
    float g[4];
    #pragma unroll
    for (int u = 0; u < 4; ++u) {
      int s = __shfl(ev.x, j + u);
      g[u] = s15[(size_t)s * NC + fl];
    }
    #pragma unroll
    for (int u = 0; u < 4; ++u) {
      union { int i; float f; } wv; wv.i = __shfl(ev.y, j + u);
      acc += wv.f * g[u];
    }
  }
  for (; j < n; ++j) {
    int s = __shfl(ev.x, j);
    union { int i; float f; } wv; wv.i = __shfl(ev.y, j);
    acc += wv.f * s15[(size_t)s * NC + fl];
  }
  acc += bf2f(bias[fl]);
  float v = (lane < NC) ? acc : -3.0e38f;
  float m = v;
  #pragma unroll
  for (int off = 32; off > 0; off >>= 1) m = fmaxf(m, __shfl_xor(m, off));
  float e = (lane < NC) ? expf(v - m) : 0.f;
  float sum = e;
  #pragma unroll
  for (int off = 32; off > 0; off >>= 1) sum += __shfl_xor(sum, off);
  if (lane < NC) out[(size_t)row * NC + lane] = v - m - logf(sum);
}

extern "C" void kernel_launch(void* const* d_in, const int* in_sizes, int n_in,
                              void* d_out, int out_size, void* d_ws, size_t ws_size,
                              hipStream_t stream) {
  const void* x   = d_in[0];
  const int* esrc = (const int*)d_in[1];
  const int* edst = (const int*)d_in[2];
  const void* ew  = d_in[3];
  const void* W0  = d_in[4];
  const void* b0  = d_in[5];
  const void* W1  = d_in[6];
  const void* b1  = d_in[7];
  const void* Wm  = d_in[8];
  const void* bm  = d_in[9];
  const void* W15 = d_in[10];
  const void* b15 = d_in[11];
  float* out = (float*)d_out;   // reference output dtype = float32

  char* ws = (char*)d_ws;
  size_t off = 0;
  auto alloc = [&](size_t bytes) -> void* {
    void* p = ws + off;
    off = (off + bytes + 255) & ~(size_t)255;
    return p;
  };
  unsigned short* xcat = (unsigned short*)alloc((size_t)NN * KCAT * 2);  // x14|...|x1
  unsigned short* xbf  = (unsigned short*)alloc((size_t)NN * 256 * 2);
  unsigned short* supp = (unsigned short*)alloc((size_t)NN * DH * 2);
  unsigned short* zbuf = (unsigned short*)alloc((size_t)NN * DH * 2);
  float* s15           = (float*)alloc((size_t)NN * NC * 4);
  int* counts          = (int*)alloc((size_t)(NN + 1) * 4);  // [NN] = dtype wild count
  int2* ell            = (int2*)alloc((size_t)NN * CAP * 8);
  unsigned short* W0T  = (unsigned short*)alloc((size_t)256 * 128 * 2);
  unsigned short* W1T  = (unsigned short*)alloc((size_t)256 * 128 * 2);
  unsigned short* WmT  = (unsigned short*)alloc((size_t)13 * 128 * 128 * 2);
  unsigned short* W15T = (unsigned short*)alloc((size_t)48 * 1792 * 2);
  unsigned short* bb   = (unsigned short*)alloc((size_t)(128 + 128 + 13 * 128 + 40) * 2);
  if (off > ws_size) return;  // signature: output stays zero
  int* flag = counts + NN;
  unsigned short* b0b  = bb;
  unsigned short* b1b  = bb + 128;
  unsigned short* bmb  = bb + 256;
  unsigned short* b15b = bb + 256 + 13 * 128;

  zero_i32<<<197, 256, 0, stream>>>(counts, NN + 1);
  detect_dtype<<<1, 256, 0, stream>>>((const unsigned short*)x, flag);
  transpose_w<<<128, 256, 0, stream>>>(W0, W0T, 1, 256, 128, 128, flag);
  transpose_w<<<128, 256, 0, stream>>>(W1, W1T, 1, 256, 128, 128, flag);
  transpose_w<<<832, 256, 0, stream>>>(Wm, WmT, 13, 128, 128, 128, flag);
  transpose_w<<<336, 256, 0, stream>>>(W15, W15T, 1, 1792, 40, 48, flag);
  convert_f<<<2048, 256, 0, stream>>>(x, xbf, NN * 256, flag);
  convert_f<<<1, 128, 0, stream>>>(b0, b0b, 128, flag);
  convert_f<<<1, 128, 0, stream>>>(b1, b1b, 128, flag);
  convert_f<<<7, 256, 0, stream>>>(bm, bmb, 13 * 128, flag);
  convert_f<<<1, 64, 0, stream>>>(b15, b15b, 40, flag);
  build_ell<<<3125, 256, 0, stream>>>(esrc, edst, ew, counts, ell, flag);

  int gb = (NN + 127) / 128;  // 391
  int sb = (NN + 3) / 4;      // 12500 (4 rows/block, wave per row)
  gemm_h<<<gb, 256, 0, stream>>>(xbf, 256, W0T, 256, zbuf, b0b);      // z = x@W0+b0
  gemm_h<<<gb, 256, 0, stream>>>(xbf, 256, W1T, 256, supp, nullptr);  // supp = x@W1
  spmm_layer<<<sb, 256, 0, stream>>>(supp, counts, ell, b1b, zbuf, DH,
                                     xcat + 13 * DH, KCAT);           // x1
  for (int l = 0; l < 13; ++l) {
    gemm_h<<<gb, 256, 0, stream>>>(xcat + (13 - l) * DH, KCAT, WmT + l * 128 * 128, 128,
                                   supp, nullptr);
    spmm_layer<<<sb, 256, 0, stream>>>(supp, counts, ell, bmb + l * DH,
                                       xcat + (13 - l) * DH, KCAT,
                                       xcat + (12 - l) * DH, KCAT);
  }
  gemm_cat<<<gb, 256, 0, stream>>>(xcat, W15T, s15);
  spmm_softmax_out<<<sb, 256, 0, stream>>>(s15, counts, ell, b15b, out);
}